// Round 1
// 85.685 us; speedup vs baseline: 1.0140x; 1.0140x over previous
//
#include <hip/hip_runtime.h>

#define SIGMA  1.0f
#define LOG2E  1.4426950408889634f
#define EPSF   1e-8f

// HW transcendentals: v_exp_f32 computes 2^x, v_log_f32 computes log2(x).
#define EXP2F(x) __builtin_amdgcn_exp2f(x)
#define LOG2F(x) __builtin_amdgcn_logf(x)

// One block per query. 256 threads = 4 waves.
// Pairwise term uses the symmetric identity (halves the work vs ordered pairs):
//   log2 sig(y) + log2 sig(-y) = -|y| - 2*log2(1 + 2^-|y|),  y = sigma*diff*log2e
// Unordered pairs enumerated cyclically: {j, (j+k) mod L}, k = 1..(L-1)/2,
// plus the antipodal k = L/2 row (j < L/2 only) when L is even. Trip count is
// block-uniform -> no triangular divergence. Mod avoided by duplicating the
// packed {score,gain} array in LDS (s_sg[i+L] = s_sg[i]).
__global__ __launch_bounds__(256) void ndcg_loss_kernel(
    const float* __restrict__ scores,
    const int*   __restrict__ relevances,
    const int*   __restrict__ qlen,
    float*       __restrict__ out,
    float invB)
{
    __shared__ float2 s_sg[256];          // [i] and [i+L] hold {score, gain}
    __shared__ int    s_cnt[5];
    __shared__ float  s_red[4][2];

    const int b   = blockIdx.x;
    const int tid = threadIdx.x;
    const int L   = qlen[b];

    if (tid < 5) s_cnt[tid] = 0;
    __syncthreads();

    if (tid < 128) {
        float sc = scores[b * 128 + tid];
        int   r  = relevances[b * 128 + tid];
        r = min(max(r, 0), 4);            // safety clamp for LDS index
        bool valid = (tid < L);
        // gains = 2^rel - 1, exact for integer grades
        float2 v = make_float2(sc, valid ? (float)((1 << r) - 1) : 0.0f);
        s_sg[tid] = v;
        if (tid < L) s_sg[tid + L] = v;   // wrap-free cyclic indexing
        if (valid) atomicAdd(&s_cnt[r], 1);
    }
    __syncthreads();

    // ---- pairwise sum over unordered pairs:
    //   acc = sum_{i<j} |g_i-g_j| * (a + 2*log2(1+2^-a)),  a = |s_i-s_j|*sigma*log2e
    // (acc == -num of the reference)
    float acc = 0.0f;
    const int j  = tid & 127;             // column/doc owned by this lane
    const int ph = tid >> 7;              // 0/1: alternate k values
    if (j < L) {
        const float sj = s_sg[j].x;
        const float gj = s_sg[j].y;
        const int Kfull = (L - 1) >> 1;   // block-uniform trip bound
        #pragma unroll 4
        for (int k = 1 + ph; k <= Kfull; k += 2) {
            const float2 v = s_sg[j + k];               // = orig[(j+k) mod L]
            float a = fabsf(v.x - sj) * (SIGMA * LOG2E);
            float u = LOG2F(1.0f + EXP2F(-a));
            acc = fmaf(fabsf(v.y - gj), fmaf(2.0f, u, a), acc);
        }
        // even L: antipodal distance L/2, each pair generated once (j < L/2)
        if (((L & 1) == 0) && ph == 0 && j < (L >> 1)) {
            const float2 v = s_sg[j + (L >> 1)];
            float a = fabsf(v.x - sj) * (SIGMA * LOG2E);
            float u = LOG2F(1.0f + EXP2F(-a));
            acc = fmaf(fabsf(v.y - gj), fmaf(2.0f, u, a), acc);
        }
    }

    // ---- ideal DCG via grade histogram (gains sorted desc = threshold lookup)
    float idcg = 0.0f;
    if (tid < 128 && tid < L) {
        int c4 = s_cnt[4], c3 = s_cnt[3], c2 = s_cnt[2], c1 = s_cnt[1];
        int t1 = c4, t2 = t1 + c3, t3 = t2 + c2, t4 = t3 + c1;
        float g = (tid < t1) ? 15.0f :
                  (tid < t2) ?  7.0f :
                  (tid < t3) ?  3.0f :
                  (tid < t4) ?  1.0f : 0.0f;
        idcg = g / LOG2F((float)(tid + 2));           // discount 1/log2(rank+2)
    }

    // ---- block reduction of (acc, idcg): wave shuffle then cross-wave LDS
    #pragma unroll
    for (int o = 32; o > 0; o >>= 1) {
        acc  += __shfl_down(acc,  o, 64);
        idcg += __shfl_down(idcg, o, 64);
    }
    const int w = tid >> 6;
    if ((tid & 63) == 0) { s_red[w][0] = acc; s_red[w][1] = idcg; }
    __syncthreads();

    if (tid == 0) {
        float n = s_red[0][0] + s_red[1][0] + s_red[2][0] + s_red[3][0];
        float d = s_red[0][1] + s_red[1][1] + s_red[2][1] + s_red[3][1];
        // per_query = -num/(idcg+eps) = acc/(idcg+eps)
        atomicAdd(out, (n / (d + EPSF)) * invB);
    }
}

extern "C" void kernel_launch(void* const* d_in, const int* in_sizes, int n_in,
                              void* d_out, int out_size, void* d_ws, size_t ws_size,
                              hipStream_t stream)
{
    const float* scores     = (const float*)d_in[0];
    const int*   relevances = (const int*)  d_in[1];
    const int*   qlen       = (const int*)  d_in[2];
    float*       out        = (float*)d_out;

    const int B = in_sizes[2];          // 2048
    // d_out is poisoned to 0xAA before every timed launch — zero it ourselves.
    (void)hipMemsetAsync(out, 0, sizeof(float) * out_size, stream);
    ndcg_loss_kernel<<<B, 256, 0, stream>>>(scores, relevances, qlen, out,
                                            1.0f / (float)B);
}